// Round 1
// baseline (623.718 us; speedup 1.0000x reference)
//
#include <hip/hip_runtime.h>

typedef unsigned short u16;
typedef __attribute__((ext_vector_type(8))) short short8;   // 8 bf16 = 4 VGPRs
typedef __attribute__((ext_vector_type(4))) float f32x4;

#define NQn 100000
#define NAn 200000
#define E1n 250000
#define E2n 250000
#define E3n 500000
#define NLn 100000
#define SLOTS 40   // max in-degree bucket capacity; Poisson(5) => P(>40) ~ 1e-22
#define EBATCH 8   // edges whose loads are issued back-to-back (latency batching)

__device__ __forceinline__ float bf2f(u16 u) {
    return __uint_as_float(((unsigned)u) << 16);
}
__device__ __forceinline__ float bf2f_lo(unsigned u) {
    return __uint_as_float(u << 16);
}
__device__ __forceinline__ float bf2f_hi(unsigned u) {
    return __uint_as_float(u & 0xffff0000u);
}
__device__ __forceinline__ u16 f2bf(float f) {
    unsigned x = __float_as_uint(f);
    unsigned r = (x + 0x7fffu + ((x >> 16) & 1u)) >> 16;
    return (u16)r;
}
__device__ __forceinline__ float sigmoidf_(float x) {
    return 1.f / (1.f + __expf(-x));
}

// -------- fold per-relation transforms into K/V weights (fp32 in, bf16 out) --------
// Wbig cols: [0,64): Wq ; [64,128): Wk@A(t0) ; [128,192): Wv@M(t0) ;
//            [192,256): Wk@A(t1) ; [256,320): Wv@M(t1)
__global__ void fold_kernel(
    const float* __restrict__ Wk, const float* __restrict__ Wv, const float* __restrict__ Wq,
    const float* __restrict__ bk, const float* __restrict__ bv, const float* __restrict__ bq,
    const float* __restrict__ a_rel, const float* __restrict__ m_rel,
    int t0, int t1, u16* __restrict__ Wbig, float* __restrict__ bbig, int NOUT)
{
    const int total = 65 * NOUT;   // 64 weight rows + 1 bias row
    for (int idx = blockIdx.x * blockDim.x + threadIdx.x; idx < total;
         idx += gridDim.x * blockDim.x) {
        const int c   = idx / NOUT;
        const int col = idx - c * NOUT;
        const int grp = col >> 6;
        const int oc  = col & 63;
        const int h   = oc >> 5, e = oc & 31;
        if (c < 64) {
            float val;
            if (grp == 0) {
                val = Wq[c * 64 + oc];
            } else {
                const int t = (grp <= 2) ? t0 : t1;
                const float* W = (grp & 1) ? Wk : Wv;
                const float* T = (grp & 1) ? a_rel : m_rel;
                float s = 0.f;
                for (int d = 0; d < 32; ++d)
                    s = fmaf(W[c * 64 + h * 32 + d],
                             T[((t * 2 + h) * 32 + d) * 32 + e], s);
                val = s;
            }
            Wbig[c * NOUT + col] = f2bf(val);
        } else {
            float val;
            if (grp == 0) {
                val = bq[oc];
            } else {
                const int t = (grp <= 2) ? t0 : t1;
                const float* B = (grp & 1) ? bk : bv;
                const float* T = (grp & 1) ? a_rel : m_rel;
                float s = 0.f;
                for (int d = 0; d < 32; ++d)
                    s = fmaf(B[h * 32 + d],
                             T[((t * 2 + h) * 32 + d) * 32 + e], s);
                val = s;
            }
            bbig[col] = val;
        }
    }
}

// -------- MFMA fused node projection --------------------------------------
// r7 lesson: 64 scalar 2-B scattered stores/wave-tile serialize the CU's
// store-address pipe (~1 addr/cyc => ~16k cyc/tile). All outputs now staged
// in the per-wave LDS tile and written as coalesced dwordx4.
template <int NOUT>
__global__ __launch_bounds__(256, 2) void node_mfma(
    const float* __restrict__ x, int N,
    const float* __restrict__ Win, const float* __restrict__ bin,
    const u16* __restrict__ Wbig, const float* __restrict__ bbig,
    u16* __restrict__ h_out, u16* __restrict__ big_out)
{
    constexpr int NT = NOUT / 16;            // stage-2 col tiles
    constexpr int NG = NT / 4;               // stage-2 64-col store groups
    __shared__ __align__(16) short sB1[4 * 4 * 64 * 8];   // [kt][nt][lane][j], 16 KB
    __shared__ __align__(16) short sB2[2 * NT * 64 * 8];  // [kt2][nt][lane][j]
    __shared__ __align__(16) short sH[4][16 * 72];        // per-wave tile, stride 72
    __shared__ float sb1[64];
    __shared__ float sb2[NOUT];

    const int tid = threadIdx.x;
    for (int idx = tid; idx < 4 * 4 * 64 * 8; idx += 256) {
        const int j = idx & 7;
        const int ln = (idx >> 3) & 63;
        const int f = idx >> 9;              // kt*4 + nt
        const int kt = f >> 2, nt = f & 3;
        const int k = kt * 32 + (ln >> 4) * 8 + j;
        const int n = nt * 16 + (ln & 15);
        sB1[idx] = (short)f2bf(Win[k * 64 + n]);
    }
    for (int idx = tid; idx < 2 * NT * 64 * 8; idx += 256) {
        const int j = idx & 7;
        const int ln = (idx >> 3) & 63;
        const int f = idx >> 9;              // kt2*NT + nt
        const int kt2 = f / NT, nt = f - kt2 * NT;
        const int k = kt2 * 32 + (ln >> 4) * 8 + j;
        const int n = nt * 16 + (ln & 15);
        sB2[idx] = (short)Wbig[k * NOUT + n];
    }
    if (tid < 64) sb1[tid] = bin[tid];
    for (int i = tid; i < NOUT; i += 256) sb2[i] = bbig[i];
    __syncthreads();

    const int wave = tid >> 6;
    const int lane = tid & 63;
    const int quad = lane >> 4;
    const int mrow = lane & 15;
    short* const myH = &sH[wave][0];
    const int srow = lane >> 2;              // store-phase row
    const int scol = (lane & 3) * 16;        // store-phase col base

    const int ntiles = (N + 63) >> 6;
    for (int tile = blockIdx.x; tile < ntiles; tile += gridDim.x) {
        const int nbase = tile * 64 + wave * 16;
        const int node = nbase + mrow;
        const bool fullgrp = (nbase + 16 <= N);

        short8 a1[4];
        if (node < N) {
            const float* xp = x + (size_t)node * 128 + quad * 8;
            #pragma unroll
            for (int kt = 0; kt < 4; ++kt) {
                const float4 u0 = *(const float4*)(xp + kt * 32);
                const float4 u1 = *(const float4*)(xp + kt * 32 + 4);
                short8 f;
                f[0] = (short)f2bf(u0.x); f[1] = (short)f2bf(u0.y);
                f[2] = (short)f2bf(u0.z); f[3] = (short)f2bf(u0.w);
                f[4] = (short)f2bf(u1.x); f[5] = (short)f2bf(u1.y);
                f[6] = (short)f2bf(u1.z); f[7] = (short)f2bf(u1.w);
                a1[kt] = f;
            }
        } else {
            #pragma unroll
            for (int kt = 0; kt < 4; ++kt) a1[kt] = short8{0,0,0,0,0,0,0,0};
        }

        // ---- stage 1: h = relu(x@Win + b1) -> myH ----
        #pragma unroll
        for (int nt = 0; nt < 4; ++nt) {
            const float bv = sb1[nt * 16 + mrow];
            f32x4 acc = {bv, bv, bv, bv};
            #pragma unroll
            for (int kt = 0; kt < 4; ++kt) {
                const short8 bf = *(const short8*)&sB1[((kt * 4 + nt) * 64 + lane) * 8];
                acc = __builtin_amdgcn_mfma_f32_16x16x32_bf16(a1[kt], bf, acc, 0, 0, 0);
            }
            #pragma unroll
            for (int r = 0; r < 4; ++r)
                myH[(quad * 4 + r) * 72 + nt * 16 + mrow] =
                    (short)f2bf(fmaxf(acc[r], 0.f));
        }

        // ---- coalesced h store: 16 rows x 128 B = 2 KB contiguous ----
        if (fullgrp) {
            const uint4 w0 = *(const uint4*)&myH[srow * 72 + scol];
            const uint4 w1 = *(const uint4*)&myH[srow * 72 + scol + 8];
            *(uint4*)(h_out + (size_t)nbase * 64 + (size_t)lane * 16) = w0;
            *(uint4*)(h_out + (size_t)nbase * 64 + (size_t)lane * 16 + 8) = w1;
        } else {
            for (int e = lane; e < 16 * 64; e += 64) {
                const int r = e >> 6, c = e & 63;
                const int nd = nbase + r;
                if (nd < N) h_out[(size_t)nd * 64 + c] = (u16)myH[r * 72 + c];
            }
        }

        // ---- stage 2: big = h @ Wbig + b2, grouped 64-col staging ----
        short8 a2[2];
        #pragma unroll
        for (int kt2 = 0; kt2 < 2; ++kt2)
            a2[kt2] = *(const short8*)&myH[mrow * 72 + kt2 * 32 + quad * 8];

        #pragma unroll
        for (int g = 0; g < NG; ++g) {
            #pragma unroll
            for (int q2 = 0; q2 < 4; ++q2) {
                const int nt = g * 4 + q2;
                const float bv = sb2[nt * 16 + mrow];
                f32x4 acc = {bv, bv, bv, bv};
                const short8 b0 = *(const short8*)&sB2[((0 * NT + nt) * 64 + lane) * 8];
                acc = __builtin_amdgcn_mfma_f32_16x16x32_bf16(a2[0], b0, acc, 0, 0, 0);
                const short8 b1 = *(const short8*)&sB2[((1 * NT + nt) * 64 + lane) * 8];
                acc = __builtin_amdgcn_mfma_f32_16x16x32_bf16(a2[1], b1, acc, 0, 0, 0);
                #pragma unroll
                for (int r = 0; r < 4; ++r)
                    myH[(quad * 4 + r) * 72 + q2 * 16 + mrow] = (short)f2bf(acc[r]);
            }
            if (fullgrp) {
                const uint4 w0 = *(const uint4*)&myH[srow * 72 + scol];
                const uint4 w1 = *(const uint4*)&myH[srow * 72 + scol + 8];
                u16* dst = big_out + (size_t)(nbase + srow) * NOUT + g * 64 + scol;
                *(uint4*)dst = w0;
                *(uint4*)(dst + 8) = w1;
            } else {
                for (int e = lane; e < 16 * 64; e += 64) {
                    const int r = e >> 6, c = e & 63;
                    const int nd = nbase + r;
                    if (nd < N)
                        big_out[(size_t)nd * NOUT + g * 64 + c] = (u16)myH[r * 72 + c];
                }
            }
        }
    }
}

// -------- scatter: bucket edges by destination (no score computation) ------
// payload.x = (src*srcStride + kBase) | relBit   (k-offset, mult of 32; v = +64)
// payload.y = bits of per-edge weight w
__global__ __launch_bounds__(256) void scatter_kernel(
    const int* __restrict__ src, const int* __restrict__ dst, int E,
    int srcStride, int kBase, int relBit, const float* __restrict__ w,
    int* __restrict__ cursor, int2* __restrict__ payload)
{
    const int e = blockIdx.x * 256 + threadIdx.x;
    if (e >= E) return;
    const int s = src[e];
    const int d = dst[e];
    if ((unsigned)d >= (unsigned)NQn) return;   // guaranteed not to happen; memory safety
    const int slot = atomicAdd(&cursor[d], 1);
    if (slot < SLOTS)
        payload[(size_t)d * SLOTS + slot] =
            make_int2((s * srcStride + kBase) | relBit, __float_as_int(w[e]));
}

// -------- gather + softmax + gelu + MFMA-Wo + skip -------------------------
// One node per 16-lane group (4 concurrent chains/wave). Latency-batched edge
// loop: all payload loads for a batch are issued back-to-back, then all K/V
// gathers, then compute — collapses cnt x (payload->KV) serial latency chain
// into ceil(cnt/EBATCH) x 2 latency hops. Wo frags + bias loaded straight from
// global into VGPRs (L2-hot, one-time) => no LDS staging, no barrier.
__global__ __launch_bounds__(256) void gather_finalize(
    const int* __restrict__ cursor, const int2* __restrict__ payload,
    const u16* __restrict__ srcArr,
    const u16* __restrict__ qArr, int qStride,
    const float* __restrict__ p_rel, int t0, int t1,
    const u16* __restrict__ h_in,
    const float* __restrict__ Wo, const float* __restrict__ bo,
    const float* __restrict__ skip, u16* __restrict__ z_out, int N)
{
    __shared__ __align__(16) short sG[4][16 * 72];     // per-wave gelu rows (bf16)
    __shared__ __align__(16) short sHh[4][16 * 72];    // per-wave h rows -> z rows

    const int tid = threadIdx.x;
    const int wave = tid >> 6, lane = tid & 63;
    const int quad = lane >> 4, mrow = lane & 15;
    const int grp = lane >> 4;       // node group 0..3
    const int gl = lane & 15;        // lane within group; holds channels 4gl..4gl+3
    const int ghead = gl >> 3;       // head of this lane's channels
    const int srow = lane >> 2;      // store-phase row
    const int scol = (lane & 3) * 16;

    // Wo B-fragments straight from global (16 KB, L2-resident): 8 x short8 = 32 VGPRs
    short8 bw[8];
    #pragma unroll
    for (int f = 0; f < 8; ++f) {
        const int kt = f >> 2, nt = f & 3;
        short8 b;
        #pragma unroll
        for (int j = 0; j < 8; ++j)
            b[j] = (short)f2bf(Wo[(kt * 32 + quad * 8 + j) * 64 + nt * 16 + mrow]);
        bw[f] = b;
    }
    // bias values this lane needs in the epilogue (one per col-tile)
    float bov4[4];
    #pragma unroll
    for (int nt = 0; nt < 4; ++nt) bov4[nt] = bo[nt * 16 + mrow];

    const float sk = sigmoidf_(skip[0]);
    const float isq = 0.17677669529663687f;   // 1/sqrt(32)
    const float s0 = p_rel[t0 * 2 + ghead] * isq;
    const float s1 = p_rel[t1 * 2 + ghead] * isq;

    short* const myG = &sG[wave][0];
    short* const myHh = &sHh[wave][0];

    const int ntiles = (N + 63) >> 6;
    for (int tile = blockIdx.x; tile < ntiles; tile += gridDim.x) {
        const int nbase = tile * 64 + wave * 16;

        // hoisted in-degree loads for all 4 chained nodes (breaks cursor->payload hop)
        int cnt4[4];
        #pragma unroll
        for (int sub = 0; sub < 4; ++sub) {
            const int node = nbase + sub * 4 + grp;
            int c = (node < N && node < NQn) ? cursor[node] : 0;
            cnt4[sub] = (c > SLOTS) ? SLOTS : c;
        }

        #pragma unroll
        for (int sub = 0; sub < 4; ++sub) {
            const int nl = sub * 4 + grp;
            const int node = nbase + nl;
            const bool valid = node < N;
            const int cnt = cnt4[sub];
            uint2 qraw = make_uint2(0, 0), hraw = make_uint2(0, 0);
            if (valid) {
                qraw = *(const uint2*)(qArr + (size_t)node * qStride + gl * 4);
                hraw = *(const uint2*)(h_in + (size_t)node * 64 + gl * 4);
            }
            const float qv0 = bf2f_lo(qraw.x), qv1 = bf2f_hi(qraw.x);
            const float qv2 = bf2f_lo(qraw.y), qv3 = bf2f_hi(qraw.y);

            const int2* pp = payload + (size_t)node * SLOTS;
            float a0 = 0.f, a1 = 0.f, a2 = 0.f, a3 = 0.f, den = 0.f;
            for (int base = 0; base < cnt; base += EBATCH) {
                const int nb = min(cnt - base, EBATCH);
                // 1) issue all payload loads (contiguous, group-uniform)
                int ex[EBATCH], ey[EBATCH];
                #pragma unroll
                for (int j = 0; j < EBATCH; ++j)
                    if (j < nb) {
                        const int2 e = pp[base + j];
                        ex[j] = e.x; ey[j] = e.y;
                    }
                // 2) issue all K/V gathers back-to-back (independent)
                uint2 kr[EBATCH], vr[EBATCH];
                #pragma unroll
                for (int j = 0; j < EBATCH; ++j)
                    if (j < nb) {
                        const int koff = ex[j] & ~31;
                        kr[j] = *(const uint2*)(srcArr + (size_t)koff + gl * 4);
                        vr[j] = *(const uint2*)(srcArr + (size_t)koff + 64 + gl * 4);
                    }
                // 3) compute
                #pragma unroll
                for (int j = 0; j < EBATCH; ++j)
                    if (j < nb) {
                        float p = qv0 * bf2f_lo(kr[j].x) + qv1 * bf2f_hi(kr[j].x)
                                + qv2 * bf2f_lo(kr[j].y) + qv3 * bf2f_hi(kr[j].y);
                        p += __shfl_xor(p, 1);   // reduce over the 8 lanes of this head
                        p += __shfl_xor(p, 2);
                        p += __shfl_xor(p, 4);
                        const float sc = (ex[j] & 1) ? s1 : s0;
                        const float exv = __expf(p * sc);
                        const float ew = exv * __int_as_float(ey[j]);
                        a0 = fmaf(ew, bf2f_lo(vr[j].x), a0);
                        a1 = fmaf(ew, bf2f_hi(vr[j].x), a1);
                        a2 = fmaf(ew, bf2f_lo(vr[j].y), a2);
                        a3 = fmaf(ew, bf2f_hi(vr[j].y), a3);
                        den += exv;
                    }
            }

            const float inv = 1.f / (den + 1e-16f);
            float gv[4] = {a0 * inv, a1 * inv, a2 * inv, a3 * inv};
            unsigned gp[2];
            #pragma unroll
            for (int j = 0; j < 4; ++j) {
                const float xx = gv[j];
                const float u = 0.7978845608028654f * (xx + 0.044715f * xx * xx * xx);
                const float th = 1.f - 2.f / (__expf(2.f * u) + 1.f);
                gv[j] = 0.5f * xx * (1.f + th);
            }
            gp[0] = (unsigned)f2bf(gv[0]) | ((unsigned)f2bf(gv[1]) << 16);
            gp[1] = (unsigned)f2bf(gv[2]) | ((unsigned)f2bf(gv[3]) << 16);
            *(uint2*)&myG[nl * 72 + gl * 4] = make_uint2(gp[0], gp[1]);
            *(uint2*)&myHh[nl * 72 + gl * 4] = hraw;
        }

        // wave-private MFMA: Z16x64 = G16x64 @ Wo64x64 (+bo), skip blend -> myHh
        short8 ag[2];
        #pragma unroll
        for (int kt = 0; kt < 2; ++kt)
            ag[kt] = *(const short8*)&myG[mrow * 72 + kt * 32 + quad * 8];

        #pragma unroll
        for (int nt = 0; nt < 4; ++nt) {
            const float bov = bov4[nt];
            f32x4 acc = {bov, bov, bov, bov};
            acc = __builtin_amdgcn_mfma_f32_16x16x32_bf16(ag[0], bw[nt], acc, 0, 0, 0);
            acc = __builtin_amdgcn_mfma_f32_16x16x32_bf16(ag[1], bw[4 + nt], acc, 0, 0, 0);
            #pragma unroll
            for (int r = 0; r < 4; ++r) {
                const int row = quad * 4 + r;
                const int a = row * 72 + nt * 16 + mrow;
                const float hv = bf2f((u16)myHh[a]);
                myHh[a] = (short)f2bf(sk * acc[r] + (1.f - sk) * hv);
            }
        }

        // coalesced z store: 16 rows x 128 B = 2 KB contiguous
        if (nbase + 16 <= N) {
            const uint4 w0 = *(const uint4*)&myHh[srow * 72 + scol];
            const uint4 w1 = *(const uint4*)&myHh[srow * 72 + scol + 8];
            *(uint4*)(z_out + (size_t)nbase * 64 + (size_t)lane * 16) = w0;
            *(uint4*)(z_out + (size_t)nbase * 64 + (size_t)lane * 16 + 8) = w1;
        } else {
            for (int e = lane; e < 16 * 64; e += 64) {
                const int r = e >> 6, c = e & 63;
                const int nd = nbase + r;
                if (nd < N) z_out[(size_t)nd * 64 + c] = (u16)myHh[r * 72 + c];
            }
        }
    }
}

// -------- decoder: sigmoid(dot64) link prediction --------------------------
__global__ __launch_bounds__(256) void decoder_kernel(
    const u16* __restrict__ z_q, const u16* __restrict__ z_a,
    const int* __restrict__ pos_idx, const int* __restrict__ neg_idx,
    float* __restrict__ out)
{
    const int gid = blockIdx.x * 256 + threadIdx.x;
    const int o = gid >> 5;         // half-wave per output
    if (o >= 2 * NLn) return;
    const int lane = threadIdx.x & 31;
    const int* idx;
    int i;
    if (o < NLn) { idx = pos_idx; i = o; }
    else         { idx = neg_idx; i = o - NLn; }
    const int r0 = idx[i];
    const int r1 = idx[NLn + i];
    const unsigned uq = *(const unsigned*)(z_q + (size_t)r0 * 64 + 2 * lane);
    const unsigned ua = *(const unsigned*)(z_a + (size_t)r1 * 64 + 2 * lane);
    float s = bf2f_lo(uq) * bf2f_lo(ua) + bf2f_hi(uq) * bf2f_hi(ua);
    s += __shfl_xor(s, 16);
    s += __shfl_xor(s, 8);
    s += __shfl_xor(s, 4);
    s += __shfl_xor(s, 2);
    s += __shfl_xor(s, 1);
    if (lane == 0) out[o] = sigmoidf_(s);
}

extern "C" void kernel_launch(void* const* d_in, const int* in_sizes, int n_in,
                              void* d_out, int out_size, void* d_ws, size_t ws_size,
                              hipStream_t stream)
{
    (void)in_sizes; (void)n_in; (void)out_size;
    const float* x_q   = (const float*)d_in[0];
    const float* x_a   = (const float*)d_in[1];
    const int* ei_qca  = (const int*)d_in[2];
    const int* ei_qwa  = (const int*)d_in[3];
    const int* ei_rev  = (const int*)d_in[4];
    const int* pos_idx = (const int*)d_in[5];
    const int* neg_idx = (const int*)d_in[6];
    const float* w_qca = (const float*)d_in[7];
    const float* w_qwa = (const float*)d_in[8];
    const float* w_rev = (const float*)d_in[9];
    const float* W_in_q = (const float*)d_in[10]; const float* b_in_q = (const float*)d_in[11];
    const float* W_in_a = (const float*)d_in[12]; const float* b_in_a = (const float*)d_in[13];
    const float* Wk_qn = (const float*)d_in[14], *bk_qn = (const float*)d_in[15];
    const float* Wq_qn = (const float*)d_in[16], *bq_qn = (const float*)d_in[17];
    const float* Wv_qn = (const float*)d_in[18], *bv_qn = (const float*)d_in[19];
    const float* Wk_an = (const float*)d_in[20], *bk_an = (const float*)d_in[21];
    const float* Wq_an = (const float*)d_in[22], *bq_an = (const float*)d_in[23];
    const float* Wv_an = (const float*)d_in[24], *bv_an = (const float*)d_in[25];
    const float* a_rel = (const float*)d_in[26];
    const float* m_rel = (const float*)d_in[27];
    const float* p_rel = (const float*)d_in[28];
    const float* Wo_qn = (const float*)d_in[29], *bo_qn = (const float*)d_in[30];
    const float* Wo_an = (const float*)d_in[31], *bo_an = (const float*)d_in[32];
    const float* skip_qn = (const float*)d_in[33], *skip_an = (const float*)d_in[34];

    char* ws = (char*)d_ws;
    size_t off = 0;
    auto alloc = [&](size_t bytes) -> char* {
        char* p = ws + off;
        off = (off + bytes + 255) & ~(size_t)255;
        return p;
    };
    u16* big_q = (u16*)alloc((size_t)NQn * 320 * 2);  // q | k0 | v0 | k1 | v1
    u16* big_a = (u16*)alloc((size_t)NAn * 192 * 2);  // q | k2 | v2
    u16* h_q   = (u16*)alloc((size_t)NQn * 64 * 2);
    u16* h_a   = (u16*)alloc((size_t)NAn * 64 * 2);
    u16* z_q   = (u16*)alloc((size_t)NQn * 64 * 2);
    u16* z_a   = (u16*)alloc((size_t)NAn * 64 * 2);
    int2* payload_a = (int2*)alloc((size_t)NQn * SLOTS * 8);  // dst of E1/E2 < NQn
    int2* payload_q = (int2*)alloc((size_t)NQn * SLOTS * 8);
    char* zero_start = ws + off;
    int* cursor_a = (int*)alloc((size_t)NQn * 4);
    int* cursor_q = (int*)alloc((size_t)NQn * 4);
    char* zero_end = ws + off;
    u16* Wbig_q = (u16*)alloc(64 * 320 * 2);
    float* bbig_q = (float*)alloc(320 * 4);
    u16* Wbig_a = (u16*)alloc(64 * 192 * 2);
    float* bbig_a = (float*)alloc(192 * 4);

    if (off > ws_size) return;  // workspace too small: leave output zeroed (visible failure)

    hipMemsetAsync(zero_start, 0, (size_t)(zero_end - zero_start), stream);

    fold_kernel<<<64, 256, 0, stream>>>(Wk_qn, Wv_qn, Wq_qn, bk_qn, bv_qn, bq_qn,
                                        a_rel, m_rel, 0, 1, Wbig_q, bbig_q, 320);
    fold_kernel<<<64, 256, 0, stream>>>(Wk_an, Wv_an, Wq_an, bk_an, bv_an, bq_an,
                                        a_rel, m_rel, 2, -1, Wbig_a, bbig_a, 192);

    node_mfma<320><<<512, 256, 0, stream>>>(x_q, NQn, W_in_q, b_in_q, Wbig_q, bbig_q, h_q, big_q);
    node_mfma<192><<<768, 256, 0, stream>>>(x_a, NAn, W_in_a, b_in_a, Wbig_a, bbig_a, h_a, big_a);

    scatter_kernel<<<(E1n + 255) / 256, 256, 0, stream>>>(
        ei_qca, ei_qca + E1n, E1n, 320, 64, 0, w_qca, cursor_a, payload_a);
    scatter_kernel<<<(E2n + 255) / 256, 256, 0, stream>>>(
        ei_qwa, ei_qwa + E2n, E2n, 320, 192, 1, w_qwa, cursor_a, payload_a);
    scatter_kernel<<<(E3n + 255) / 256, 256, 0, stream>>>(
        ei_rev, ei_rev + E3n, E3n, 192, 64, 0, w_rev, cursor_q, payload_q);

    // answer-node aggregation: edges from q-nodes (big_q), q rows in big_a
    gather_finalize<<<3136, 256, 0, stream>>>(
        cursor_a, payload_a, big_q, big_a, 192, p_rel, 0, 1,
        h_a, Wo_an, bo_an, skip_an, z_a, NAn);
    // question-node aggregation: edges from a-nodes (big_a), q rows in big_q
    gather_finalize<<<1568, 256, 0, stream>>>(
        cursor_q, payload_q, big_a, big_q, 320, p_rel, 2, 2,
        h_q, Wo_qn, bo_qn, skip_qn, z_q, NQn);

    decoder_kernel<<<(2 * NLn * 32 + 255) / 256, 256, 0, stream>>>(
        z_q, z_a, pos_idx, neg_idx, (float*)d_out);
}

// Round 2
// 484.560 us; speedup vs baseline: 1.2872x; 1.2872x over previous
//
#include <hip/hip_runtime.h>

typedef unsigned short u16;
typedef __attribute__((ext_vector_type(8))) short short8;   // 8 bf16 = 4 VGPRs
typedef __attribute__((ext_vector_type(4))) float f32x4;

#define NQn 100000
#define NAn 200000
#define E1n 250000
#define E2n 250000
#define E3n 500000
#define NLn 100000
#define SLOTS 40   // max in-degree bucket capacity; Poisson(5) => P(>40) ~ 1e-22

__device__ __forceinline__ float bf2f(u16 u) {
    return __uint_as_float(((unsigned)u) << 16);
}
__device__ __forceinline__ float bf2f_lo(unsigned u) {
    return __uint_as_float(u << 16);
}
__device__ __forceinline__ float bf2f_hi(unsigned u) {
    return __uint_as_float(u & 0xffff0000u);
}
__device__ __forceinline__ u16 f2bf(float f) {
    unsigned x = __float_as_uint(f);
    unsigned r = (x + 0x7fffu + ((x >> 16) & 1u)) >> 16;
    return (u16)r;
}
__device__ __forceinline__ float sigmoidf_(float x) {
    return 1.f / (1.f + __expf(-x));
}

// -------- fold per-relation transforms into K/V weights (fp32 in, bf16 out) --------
// Wbig cols: [0,64): Wq ; [64,128): Wk@A(t0) ; [128,192): Wv@M(t0) ;
//            [192,256): Wk@A(t1) ; [256,320): Wv@M(t1)
__global__ void fold_kernel(
    const float* __restrict__ Wk, const float* __restrict__ Wv, const float* __restrict__ Wq,
    const float* __restrict__ bk, const float* __restrict__ bv, const float* __restrict__ bq,
    const float* __restrict__ a_rel, const float* __restrict__ m_rel,
    int t0, int t1, u16* __restrict__ Wbig, float* __restrict__ bbig, int NOUT)
{
    const int total = 65 * NOUT;   // 64 weight rows + 1 bias row
    for (int idx = blockIdx.x * blockDim.x + threadIdx.x; idx < total;
         idx += gridDim.x * blockDim.x) {
        const int c   = idx / NOUT;
        const int col = idx - c * NOUT;
        const int grp = col >> 6;
        const int oc  = col & 63;
        const int h   = oc >> 5, e = oc & 31;
        if (c < 64) {
            float val;
            if (grp == 0) {
                val = Wq[c * 64 + oc];
            } else {
                const int t = (grp <= 2) ? t0 : t1;
                const float* W = (grp & 1) ? Wk : Wv;
                const float* T = (grp & 1) ? a_rel : m_rel;
                float s = 0.f;
                for (int d = 0; d < 32; ++d)
                    s = fmaf(W[c * 64 + h * 32 + d],
                             T[((t * 2 + h) * 32 + d) * 32 + e], s);
                val = s;
            }
            Wbig[c * NOUT + col] = f2bf(val);
        } else {
            float val;
            if (grp == 0) {
                val = bq[oc];
            } else {
                const int t = (grp <= 2) ? t0 : t1;
                const float* B = (grp & 1) ? bk : bv;
                const float* T = (grp & 1) ? a_rel : m_rel;
                float s = 0.f;
                for (int d = 0; d < 32; ++d)
                    s = fmaf(B[h * 32 + d],
                             T[((t * 2 + h) * 32 + d) * 32 + e], s);
                val = s;
            }
            bbig[col] = val;
        }
    }
}

// -------- pre-transform Wo (64x64 f32) into MFMA fragment layout (bf16) ----
// Wof[(f*64+ln)*8+j] = Wo[(kt*32+(ln>>4)*8+j)*64 + nt*16+(ln&15)], f=kt*4+nt.
// Lets gather_finalize load B-fragments as 8 transient dwordx4 from L2 instead
// of holding 32 persistent VGPRs (r1 lesson: that crossed the 64-VGPR cliff).
__global__ void fold_wo(const float* __restrict__ WoA, u16* __restrict__ WofA,
                        const float* __restrict__ WoQ, u16* __restrict__ WofQ)
{
    const int idx = blockIdx.x * 256 + threadIdx.x;
    if (idx >= 2 * 4096) return;
    const float* Wo = (idx < 4096) ? WoA : WoQ;
    u16* Wof = (idx < 4096) ? WofA : WofQ;
    const int t = idx & 4095;
    const int j = t & 7, ln = (t >> 3) & 63, f = t >> 9;
    const int kt = f >> 2, nt = f & 3;
    const int k = kt * 32 + (ln >> 4) * 8 + j;
    const int n = nt * 16 + (ln & 15);
    Wof[t] = f2bf(Wo[k * 64 + n]);
}

// -------- MFMA fused node projection --------------------------------------
template <int NOUT>
__global__ __launch_bounds__(256, 2) void node_mfma(
    const float* __restrict__ x, int N,
    const float* __restrict__ Win, const float* __restrict__ bin,
    const u16* __restrict__ Wbig, const float* __restrict__ bbig,
    u16* __restrict__ h_out, u16* __restrict__ big_out)
{
    constexpr int NT = NOUT / 16;            // stage-2 col tiles
    constexpr int NG = NT / 4;               // stage-2 64-col store groups
    __shared__ __align__(16) short sB1[4 * 4 * 64 * 8];   // [kt][nt][lane][j], 16 KB
    __shared__ __align__(16) short sB2[2 * NT * 64 * 8];  // [kt2][nt][lane][j]
    __shared__ __align__(16) short sH[4][16 * 72];        // per-wave tile, stride 72
    __shared__ float sb1[64];
    __shared__ float sb2[NOUT];

    const int tid = threadIdx.x;
    for (int idx = tid; idx < 4 * 4 * 64 * 8; idx += 256) {
        const int j = idx & 7;
        const int ln = (idx >> 3) & 63;
        const int f = idx >> 9;              // kt*4 + nt
        const int kt = f >> 2, nt = f & 3;
        const int k = kt * 32 + (ln >> 4) * 8 + j;
        const int n = nt * 16 + (ln & 15);
        sB1[idx] = (short)f2bf(Win[k * 64 + n]);
    }
    for (int idx = tid; idx < 2 * NT * 64 * 8; idx += 256) {
        const int j = idx & 7;
        const int ln = (idx >> 3) & 63;
        const int f = idx >> 9;              // kt2*NT + nt
        const int kt2 = f / NT, nt = f - kt2 * NT;
        const int k = kt2 * 32 + (ln >> 4) * 8 + j;
        const int n = nt * 16 + (ln & 15);
        sB2[idx] = (short)Wbig[k * NOUT + n];
    }
    if (tid < 64) sb1[tid] = bin[tid];
    for (int i = tid; i < NOUT; i += 256) sb2[i] = bbig[i];
    __syncthreads();

    const int wave = tid >> 6;
    const int lane = tid & 63;
    const int quad = lane >> 4;
    const int mrow = lane & 15;
    short* const myH = &sH[wave][0];
    const int srow = lane >> 2;              // store-phase row
    const int scol = (lane & 3) * 16;        // store-phase col base

    const int ntiles = (N + 63) >> 6;
    for (int tile = blockIdx.x; tile < ntiles; tile += gridDim.x) {
        const int nbase = tile * 64 + wave * 16;
        const int node = nbase + mrow;
        const bool fullgrp = (nbase + 16 <= N);

        short8 a1[4];
        if (node < N) {
            const float* xp = x + (size_t)node * 128 + quad * 8;
            #pragma unroll
            for (int kt = 0; kt < 4; ++kt) {
                const float4 u0 = *(const float4*)(xp + kt * 32);
                const float4 u1 = *(const float4*)(xp + kt * 32 + 4);
                short8 f;
                f[0] = (short)f2bf(u0.x); f[1] = (short)f2bf(u0.y);
                f[2] = (short)f2bf(u0.z); f[3] = (short)f2bf(u0.w);
                f[4] = (short)f2bf(u1.x); f[5] = (short)f2bf(u1.y);
                f[6] = (short)f2bf(u1.z); f[7] = (short)f2bf(u1.w);
                a1[kt] = f;
            }
        } else {
            #pragma unroll
            for (int kt = 0; kt < 4; ++kt) a1[kt] = short8{0,0,0,0,0,0,0,0};
        }

        // ---- stage 1: h = relu(x@Win + b1) -> myH ----
        #pragma unroll
        for (int nt = 0; nt < 4; ++nt) {
            const float bv = sb1[nt * 16 + mrow];
            f32x4 acc = {bv, bv, bv, bv};
            #pragma unroll
            for (int kt = 0; kt < 4; ++kt) {
                const short8 bf = *(const short8*)&sB1[((kt * 4 + nt) * 64 + lane) * 8];
                acc = __builtin_amdgcn_mfma_f32_16x16x32_bf16(a1[kt], bf, acc, 0, 0, 0);
            }
            #pragma unroll
            for (int r = 0; r < 4; ++r)
                myH[(quad * 4 + r) * 72 + nt * 16 + mrow] =
                    (short)f2bf(fmaxf(acc[r], 0.f));
        }

        // ---- coalesced h store: 16 rows x 128 B = 2 KB contiguous ----
        if (fullgrp) {
            const uint4 w0 = *(const uint4*)&myH[srow * 72 + scol];
            const uint4 w1 = *(const uint4*)&myH[srow * 72 + scol + 8];
            *(uint4*)(h_out + (size_t)nbase * 64 + (size_t)lane * 16) = w0;
            *(uint4*)(h_out + (size_t)nbase * 64 + (size_t)lane * 16 + 8) = w1;
        } else {
            for (int e = lane; e < 16 * 64; e += 64) {
                const int r = e >> 6, c = e & 63;
                const int nd = nbase + r;
                if (nd < N) h_out[(size_t)nd * 64 + c] = (u16)myH[r * 72 + c];
            }
        }

        // ---- stage 2: big = h @ Wbig + b2, grouped 64-col staging ----
        short8 a2[2];
        #pragma unroll
        for (int kt2 = 0; kt2 < 2; ++kt2)
            a2[kt2] = *(const short8*)&myH[mrow * 72 + kt2 * 32 + quad * 8];

        #pragma unroll
        for (int g = 0; g < NG; ++g) {
            #pragma unroll
            for (int q2 = 0; q2 < 4; ++q2) {
                const int nt = g * 4 + q2;
                const float bv = sb2[nt * 16 + mrow];
                f32x4 acc = {bv, bv, bv, bv};
                const short8 b0 = *(const short8*)&sB2[((0 * NT + nt) * 64 + lane) * 8];
                acc = __builtin_amdgcn_mfma_f32_16x16x32_bf16(a2[0], b0, acc, 0, 0, 0);
                const short8 b1 = *(const short8*)&sB2[((1 * NT + nt) * 64 + lane) * 8];
                acc = __builtin_amdgcn_mfma_f32_16x16x32_bf16(a2[1], b1, acc, 0, 0, 0);
                #pragma unroll
                for (int r = 0; r < 4; ++r)
                    myH[(quad * 4 + r) * 72 + q2 * 16 + mrow] = (short)f2bf(acc[r]);
            }
            if (fullgrp) {
                const uint4 w0 = *(const uint4*)&myH[srow * 72 + scol];
                const uint4 w1 = *(const uint4*)&myH[srow * 72 + scol + 8];
                u16* dst = big_out + (size_t)(nbase + srow) * NOUT + g * 64 + scol;
                *(uint4*)dst = w0;
                *(uint4*)(dst + 8) = w1;
            } else {
                for (int e = lane; e < 16 * 64; e += 64) {
                    const int r = e >> 6, c = e & 63;
                    const int nd = nbase + r;
                    if (nd < N)
                        big_out[(size_t)nd * NOUT + g * 64 + c] = (u16)myH[r * 72 + c];
                }
            }
        }
    }
}

// -------- scatter: bucket edges by destination (no score computation) ------
// payload.x = (src*srcStride + kBase) | relBit   (k-offset, mult of 32; v = +64)
// payload.y = bits of per-edge weight w
__global__ __launch_bounds__(256) void scatter_kernel(
    const int* __restrict__ src, const int* __restrict__ dst, int E,
    int srcStride, int kBase, int relBit, const float* __restrict__ w,
    int* __restrict__ cursor, int2* __restrict__ payload)
{
    const int e = blockIdx.x * 256 + threadIdx.x;
    if (e >= E) return;
    const int s = src[e];
    const int d = dst[e];
    if ((unsigned)d >= (unsigned)NQn) return;   // guaranteed not to happen; memory safety
    const int slot = atomicAdd(&cursor[d], 1);
    if (slot < SLOTS)
        payload[(size_t)d * SLOTS + slot] =
            make_int2((s * srcStride + kBase) | relBit, __float_as_int(w[e]));
}

// -------- gather + softmax + gelu + MFMA-Wo + skip -------------------------
// Merged A-side + Q-side launch (block range selects side). One node per
// 8-lane group => 8 concurrent edge-chains/wave, 2 serial subs (r1 post-mortem:
// MLP must come from more chains, not per-thread batch arrays). Wo fragments
// loaded transiently from a pre-folded L2-hot buffer; no LDS staging for them,
// no barrier, and <=64 VGPR target via __launch_bounds__(256,8) to stay on the
// 8-waves/SIMD occupancy tier.
struct GArgs {
    const int* cursor; const int2* payload; const u16* srcArr;
    const u16* qArr; const u16* h_in;
    const u16* Wof; const float* bo; const float* skip;
    u16* z_out;
    int qStride; int N; int ntiles; int t0; int t1;
};

__global__ __launch_bounds__(256, 8) void gather_finalize(
    GArgs A, GArgs Q, const float* __restrict__ p_rel)
{
    __shared__ __align__(16) short sG[4][16 * 72];     // per-wave gelu rows (bf16)
    __shared__ __align__(16) short sHh[4][16 * 72];    // per-wave h rows -> z rows

    const bool isA = (int)blockIdx.x < A.ntiles;
    const GArgs& G = isA ? A : Q;
    const int tile = isA ? (int)blockIdx.x : (int)blockIdx.x - A.ntiles;

    const int tid = threadIdx.x;
    const int wave = tid >> 6, lane = tid & 63;
    const int quad = lane >> 4, mrow = lane & 15;
    const int grp = lane >> 3;       // node group 0..7
    const int gl = lane & 7;         // lane within group; holds channels 8gl..8gl+7
    const int ghead = gl >> 2;       // head of this lane's channels
    const int srow = lane >> 2;      // store-phase row
    const int scol = (lane & 3) * 16;

    const float sk = sigmoidf_(G.skip[0]);
    const float isq = 0.17677669529663687f;   // 1/sqrt(32)
    const float s0 = p_rel[G.t0 * 2 + ghead] * isq;
    const float s1 = p_rel[G.t1 * 2 + ghead] * isq;

    short* const myG = &sG[wave][0];
    short* const myHh = &sHh[wave][0];

    const int N = G.N;
    const int nbase = tile * 64 + wave * 16;

    // hoisted in-degree loads for both subs (breaks cursor->payload hop)
    int cnt2[2];
    #pragma unroll
    for (int sub = 0; sub < 2; ++sub) {
        const int node = nbase + sub * 8 + grp;
        int c = (node < N && node < NQn) ? G.cursor[node] : 0;
        cnt2[sub] = (c > SLOTS) ? SLOTS : c;
    }

    #pragma unroll
    for (int sub = 0; sub < 2; ++sub) {
        const int nl = sub * 8 + grp;
        const int node = nbase + nl;
        const bool valid = node < N;
        const int cnt = cnt2[sub];
        uint4 qraw = make_uint4(0, 0, 0, 0), hraw = make_uint4(0, 0, 0, 0);
        if (valid) {
            qraw = *(const uint4*)(G.qArr + (size_t)node * G.qStride + gl * 8);
            hraw = *(const uint4*)(G.h_in + (size_t)node * 64 + gl * 8);
        }
        *(uint4*)&myHh[nl * 72 + gl * 8] = hraw;
        const float qv0 = bf2f_lo(qraw.x), qv1 = bf2f_hi(qraw.x);
        const float qv2 = bf2f_lo(qraw.y), qv3 = bf2f_hi(qraw.y);
        const float qv4 = bf2f_lo(qraw.z), qv5 = bf2f_hi(qraw.z);
        const float qv6 = bf2f_lo(qraw.w), qv7 = bf2f_hi(qraw.w);

        const int2* pp = G.payload + (size_t)node * SLOTS;
        float a0 = 0.f, a1 = 0.f, a2 = 0.f, a3 = 0.f;
        float a4 = 0.f, a5 = 0.f, a6 = 0.f, a7 = 0.f, den = 0.f;
        int2 e = make_int2(0, 0);
        if (cnt > 0) e = pp[0];
        for (int i = 0; i < cnt; ++i) {
            const int2 ec = e;
            if (i + 1 < cnt) e = pp[i + 1];      // prefetch: payload off critical path
            const int koff = ec.x & ~31;
            const uint4 kr = *(const uint4*)(G.srcArr + (size_t)koff + gl * 8);
            const uint4 vr = *(const uint4*)(G.srcArr + (size_t)koff + 64 + gl * 8);
            float p = qv0 * bf2f_lo(kr.x) + qv1 * bf2f_hi(kr.x)
                    + qv2 * bf2f_lo(kr.y) + qv3 * bf2f_hi(kr.y)
                    + qv4 * bf2f_lo(kr.z) + qv5 * bf2f_hi(kr.z)
                    + qv6 * bf2f_lo(kr.w) + qv7 * bf2f_hi(kr.w);
            p += __shfl_xor(p, 1);   // reduce over the 4 lanes of this head
            p += __shfl_xor(p, 2);
            const float sc = (ec.x & 1) ? s1 : s0;
            const float exv = __expf(p * sc);
            const float ew = exv * __int_as_float(ec.y);
            a0 = fmaf(ew, bf2f_lo(vr.x), a0); a1 = fmaf(ew, bf2f_hi(vr.x), a1);
            a2 = fmaf(ew, bf2f_lo(vr.y), a2); a3 = fmaf(ew, bf2f_hi(vr.y), a3);
            a4 = fmaf(ew, bf2f_lo(vr.z), a4); a5 = fmaf(ew, bf2f_hi(vr.z), a5);
            a6 = fmaf(ew, bf2f_lo(vr.w), a6); a7 = fmaf(ew, bf2f_hi(vr.w), a7);
            den += exv;
        }

        const float inv = 1.f / (den + 1e-16f);
        float gv[8] = {a0 * inv, a1 * inv, a2 * inv, a3 * inv,
                       a4 * inv, a5 * inv, a6 * inv, a7 * inv};
        #pragma unroll
        for (int j = 0; j < 8; ++j) {
            const float xx = gv[j];
            const float u = 0.7978845608028654f * (xx + 0.044715f * xx * xx * xx);
            const float th = 1.f - 2.f / (__expf(2.f * u) + 1.f);
            gv[j] = 0.5f * xx * (1.f + th);
        }
        uint4 gp;
        gp.x = (unsigned)f2bf(gv[0]) | ((unsigned)f2bf(gv[1]) << 16);
        gp.y = (unsigned)f2bf(gv[2]) | ((unsigned)f2bf(gv[3]) << 16);
        gp.z = (unsigned)f2bf(gv[4]) | ((unsigned)f2bf(gv[5]) << 16);
        gp.w = (unsigned)f2bf(gv[6]) | ((unsigned)f2bf(gv[7]) << 16);
        *(uint4*)&myG[nl * 72 + gl * 8] = gp;
    }

    // wave-private MFMA: Z16x64 = G16x64 @ Wo64x64 (+bo), skip blend -> myHh
    short8 ag[2];
    #pragma unroll
    for (int kt = 0; kt < 2; ++kt)
        ag[kt] = *(const short8*)&myG[mrow * 72 + kt * 32 + quad * 8];

    #pragma unroll
    for (int nt = 0; nt < 4; ++nt) {
        const float bov = G.bo[nt * 16 + mrow];
        f32x4 acc = {bov, bov, bov, bov};
        const short8 b0 = *(const short8*)&G.Wof[((0 * 4 + nt) * 64 + lane) * 8];
        acc = __builtin_amdgcn_mfma_f32_16x16x32_bf16(ag[0], b0, acc, 0, 0, 0);
        const short8 b1 = *(const short8*)&G.Wof[((1 * 4 + nt) * 64 + lane) * 8];
        acc = __builtin_amdgcn_mfma_f32_16x16x32_bf16(ag[1], b1, acc, 0, 0, 0);
        #pragma unroll
        for (int r = 0; r < 4; ++r) {
            const int row = quad * 4 + r;
            const int a = row * 72 + nt * 16 + mrow;
            const float hv = bf2f((u16)myHh[a]);
            myHh[a] = (short)f2bf(sk * acc[r] + (1.f - sk) * hv);
        }
    }

    // coalesced z store: 16 rows x 128 B = 2 KB contiguous
    if (nbase + 16 <= N) {
        const uint4 w0 = *(const uint4*)&myHh[srow * 72 + scol];
        const uint4 w1 = *(const uint4*)&myHh[srow * 72 + scol + 8];
        *(uint4*)(G.z_out + (size_t)nbase * 64 + (size_t)lane * 16) = w0;
        *(uint4*)(G.z_out + (size_t)nbase * 64 + (size_t)lane * 16 + 8) = w1;
    } else {
        for (int e2 = lane; e2 < 16 * 64; e2 += 64) {
            const int r = e2 >> 6, c = e2 & 63;
            const int nd = nbase + r;
            if (nd < N) G.z_out[(size_t)nd * 64 + c] = (u16)myHh[r * 72 + c];
        }
    }
}

// -------- decoder: sigmoid(dot64) link prediction --------------------------
__global__ __launch_bounds__(256) void decoder_kernel(
    const u16* __restrict__ z_q, const u16* __restrict__ z_a,
    const int* __restrict__ pos_idx, const int* __restrict__ neg_idx,
    float* __restrict__ out)
{
    const int gid = blockIdx.x * 256 + threadIdx.x;
    const int o = gid >> 5;         // half-wave per output
    if (o >= 2 * NLn) return;
    const int lane = threadIdx.x & 31;
    const int* idx;
    int i;
    if (o < NLn) { idx = pos_idx; i = o; }
    else         { idx = neg_idx; i = o - NLn; }
    const int r0 = idx[i];
    const int r1 = idx[NLn + i];
    const unsigned uq = *(const unsigned*)(z_q + (size_t)r0 * 64 + 2 * lane);
    const unsigned ua = *(const unsigned*)(z_a + (size_t)r1 * 64 + 2 * lane);
    float s = bf2f_lo(uq) * bf2f_lo(ua) + bf2f_hi(uq) * bf2f_hi(ua);
    s += __shfl_xor(s, 16);
    s += __shfl_xor(s, 8);
    s += __shfl_xor(s, 4);
    s += __shfl_xor(s, 2);
    s += __shfl_xor(s, 1);
    if (lane == 0) out[o] = sigmoidf_(s);
}

extern "C" void kernel_launch(void* const* d_in, const int* in_sizes, int n_in,
                              void* d_out, int out_size, void* d_ws, size_t ws_size,
                              hipStream_t stream)
{
    (void)in_sizes; (void)n_in; (void)out_size;
    const float* x_q   = (const float*)d_in[0];
    const float* x_a   = (const float*)d_in[1];
    const int* ei_qca  = (const int*)d_in[2];
    const int* ei_qwa  = (const int*)d_in[3];
    const int* ei_rev  = (const int*)d_in[4];
    const int* pos_idx = (const int*)d_in[5];
    const int* neg_idx = (const int*)d_in[6];
    const float* w_qca = (const float*)d_in[7];
    const float* w_qwa = (const float*)d_in[8];
    const float* w_rev = (const float*)d_in[9];
    const float* W_in_q = (const float*)d_in[10]; const float* b_in_q = (const float*)d_in[11];
    const float* W_in_a = (const float*)d_in[12]; const float* b_in_a = (const float*)d_in[13];
    const float* Wk_qn = (const float*)d_in[14], *bk_qn = (const float*)d_in[15];
    const float* Wq_qn = (const float*)d_in[16], *bq_qn = (const float*)d_in[17];
    const float* Wv_qn = (const float*)d_in[18], *bv_qn = (const float*)d_in[19];
    const float* Wk_an = (const float*)d_in[20], *bk_an = (const float*)d_in[21];
    const float* Wq_an = (const float*)d_in[22], *bq_an = (const float*)d_in[23];
    const float* Wv_an = (const float*)d_in[24], *bv_an = (const float*)d_in[25];
    const float* a_rel = (const float*)d_in[26];
    const float* m_rel = (const float*)d_in[27];
    const float* p_rel = (const float*)d_in[28];
    const float* Wo_qn = (const float*)d_in[29], *bo_qn = (const float*)d_in[30];
    const float* Wo_an = (const float*)d_in[31], *bo_an = (const float*)d_in[32];
    const float* skip_qn = (const float*)d_in[33], *skip_an = (const float*)d_in[34];

    char* ws = (char*)d_ws;
    size_t off = 0;
    auto alloc = [&](size_t bytes) -> char* {
        char* p = ws + off;
        off = (off + bytes + 255) & ~(size_t)255;
        return p;
    };
    u16* big_q = (u16*)alloc((size_t)NQn * 320 * 2);  // q | k0 | v0 | k1 | v1
    u16* big_a = (u16*)alloc((size_t)NAn * 192 * 2);  // q | k2 | v2
    u16* h_q   = (u16*)alloc((size_t)NQn * 64 * 2);
    u16* h_a   = (u16*)alloc((size_t)NAn * 64 * 2);
    u16* z_q   = (u16*)alloc((size_t)NQn * 64 * 2);
    u16* z_a   = (u16*)alloc((size_t)NAn * 64 * 2);
    int2* payload_a = (int2*)alloc((size_t)NQn * SLOTS * 8);  // dst of E1/E2 < NQn
    int2* payload_q = (int2*)alloc((size_t)NQn * SLOTS * 8);
    char* zero_start = ws + off;
    int* cursor_a = (int*)alloc((size_t)NQn * 4);
    int* cursor_q = (int*)alloc((size_t)NQn * 4);
    char* zero_end = ws + off;
    u16* Wbig_q = (u16*)alloc(64 * 320 * 2);
    float* bbig_q = (float*)alloc(320 * 4);
    u16* Wbig_a = (u16*)alloc(64 * 192 * 2);
    float* bbig_a = (float*)alloc(192 * 4);
    u16* Wof_a = (u16*)alloc(4096 * 2);
    u16* Wof_q = (u16*)alloc(4096 * 2);

    if (off > ws_size) return;  // workspace too small: leave output zeroed (visible failure)

    hipMemsetAsync(zero_start, 0, (size_t)(zero_end - zero_start), stream);

    fold_kernel<<<64, 256, 0, stream>>>(Wk_qn, Wv_qn, Wq_qn, bk_qn, bv_qn, bq_qn,
                                        a_rel, m_rel, 0, 1, Wbig_q, bbig_q, 320);
    fold_kernel<<<64, 256, 0, stream>>>(Wk_an, Wv_an, Wq_an, bk_an, bv_an, bq_an,
                                        a_rel, m_rel, 2, -1, Wbig_a, bbig_a, 192);
    fold_wo<<<32, 256, 0, stream>>>(Wo_an, Wof_a, Wo_qn, Wof_q);

    node_mfma<320><<<512, 256, 0, stream>>>(x_q, NQn, W_in_q, b_in_q, Wbig_q, bbig_q, h_q, big_q);
    node_mfma<192><<<768, 256, 0, stream>>>(x_a, NAn, W_in_a, b_in_a, Wbig_a, bbig_a, h_a, big_a);

    scatter_kernel<<<(E1n + 255) / 256, 256, 0, stream>>>(
        ei_qca, ei_qca + E1n, E1n, 320, 64, 0, w_qca, cursor_a, payload_a);
    scatter_kernel<<<(E2n + 255) / 256, 256, 0, stream>>>(
        ei_qwa, ei_qwa + E2n, E2n, 320, 192, 1, w_qwa, cursor_a, payload_a);
    scatter_kernel<<<(E3n + 255) / 256, 256, 0, stream>>>(
        ei_rev, ei_rev + E3n, E3n, 192, 64, 0, w_rev, cursor_q, payload_q);

    // merged gather: blocks [0, ntA) = answer side, [ntA, ntA+ntQ) = question side
    const int ntA = (NAn + 63) >> 6;   // 3125
    const int ntQ = (NQn + 63) >> 6;   // 1563
    GArgs A, Q;
    A.cursor = cursor_a; A.payload = payload_a; A.srcArr = big_q;
    A.qArr = big_a; A.h_in = h_a; A.Wof = Wof_a; A.bo = bo_an; A.skip = skip_an;
    A.z_out = z_a; A.qStride = 192; A.N = NAn; A.ntiles = ntA; A.t0 = 0; A.t1 = 1;
    Q.cursor = cursor_q; Q.payload = payload_q; Q.srcArr = big_a;
    Q.qArr = big_q; Q.h_in = h_q; Q.Wof = Wof_q; Q.bo = bo_qn; Q.skip = skip_qn;
    Q.z_out = z_q; Q.qStride = 320; Q.N = NQn; Q.ntiles = ntQ; Q.t0 = 2; Q.t1 = 2;
    gather_finalize<<<ntA + ntQ, 256, 0, stream>>>(A, Q, p_rel);

    decoder_kernel<<<(2 * NLn * 32 + 255) / 256, 256, 0, stream>>>(
        z_q, z_a, pos_idx, neg_idx, (float*)d_out);
}